// Round 13
// baseline (1866.721 us; speedup 1.0000x reference)
//
#include <hip/hip_runtime.h>
#include <hip/hip_bf16.h>
#include <math.h>

#define BTOT   16384
#define NLAYER 24
#define HID    192
#define NDIN   12
#define NBASE  66
#define EPSP   1e-3f
#define EPB    64        // elements per block; 768 threads; grid 256 -> 1 round/CU

// ------------- LDS layout (bytes), 156,448 total, dynamic -------------
#define EST 200          // j/k stride (shorts) for sH1b/sGb rows
#define W3ST 17          // sW3f row stride in floats (full bank rotation)
#define OB_H1  0         // ushort[64*200]  25600 : h1 bf16 [e][k]
#define OB_G   25600     // ushort[192*200] 76800 : G bf16 [col][j], col=r*32+e_half
#define OB_M2  102400    // uint[64*8]       2048 : h2 relu bitmask [e][j-word]
#define OB_R   104448    // float[72*64]    18432 : cotangent rows [rt][e]
#define OB_W1  122880    // ushort[192*8]    3072 : W1 bf16 rows padded to 8
#define OB_W3F 125952    // float[192*17]   13056 : W3 fp32 [j][t], stride 17
#define OB_PRM 139008    // float[2][12*64]  6144 : prm sums / tf,es (parity dbuf)
#define OB_GZ  145152    // float[6*384]     9216 : g_z1 sums [i][r*64+e] (atomics)
#define OB_Z1  154368    // float[6*64]      1536 : z[6..12) for next F1
#define OB_LD  155904    // float[64]         256 : logdet acc
#define OB_ZQ  156160    // float[64]         256 : sum z^2
#define OB_RED 156416    // float[8]           32
#define SMEM_BYTES 156448

typedef __attribute__((ext_vector_type(8))) short s8v;
typedef __attribute__((ext_vector_type(4))) float f4v;
#define MFMA16(a,b,c) __builtin_amdgcn_mfma_f32_16x16x32_bf16(a,b,c,0,0,0)

__device__ __forceinline__ unsigned short f2bf(float f) {
  unsigned u = __builtin_bit_cast(unsigned, f);
  u += 0x7fffu + ((u >> 16) & 1u);          // RNE
  return (unsigned short)(u >> 16);
}
__device__ __forceinline__ float bf2f(unsigned short h) {
  unsigned u = ((unsigned)h) << 16;
  return __builtin_bit_cast(float, u);
}
__device__ __forceinline__ unsigned pk2(float a, float b) {
  return (unsigned)f2bf(a) | ((unsigned)f2bf(b) << 16);
}
__device__ __forceinline__ float blo(unsigned u) { return bf2f((unsigned short)(u & 0xffff)); }
__device__ __forceinline__ float bhi(unsigned u) { return bf2f((unsigned short)(u >> 16)); }

// ---------------------------------------------------------------------
__global__ void prep_kernel(const float* __restrict__ W2,
                            unsigned short* __restrict__ w2b,
                            unsigned short* __restrict__ w2t) {
  int idx = blockIdx.x * 256 + threadIdx.x;   // 884736 exact
  int l   = idx / (HID * HID);
  int rem = idx - l * HID * HID;
  int k   = rem / HID;
  int j   = rem - k * HID;
  w2b[idx] = f2bf(W2[idx]);                         // [l][j][k]
  w2t[idx] = f2bf(W2[l * HID * HID + j * HID + k]); // [l][k][j]
}

// ---------------------------------------------------------------------
// flow_kernel: block = 64 elements, 768 threads (12 waves), grid 256 ->
// exactly ONE block-round per CU (R12 evidence: waves don't help, the
// serial phase chain does; 48 -> 24 sequential layer-iterations per CU).
// h2 values are never read from LDS (prm from registers, V2 needs only
// the relu mask) -> 2KB bitmask replaces 25KB of h2 storage.
// V2/V3 run per 32-col half (G buffer shared): 7 barriers/layer, 1 round.
__global__ __launch_bounds__(768) void flow_kernel(
    float* __restrict__ yz, float* __restrict__ jp,
    const float* __restrict__ W1, const float* __restrict__ b1,
    const float* __restrict__ b2,
    const float* __restrict__ W3, const float* __restrict__ b3,
    const unsigned short* __restrict__ w2b,
    const unsigned short* __restrict__ w2t,
    float* __restrict__ ws_sum, float* __restrict__ out_lp) {
  extern __shared__ char smraw[];
  unsigned short* sH1b = (unsigned short*)(smraw + OB_H1);
  unsigned short* sGb  = (unsigned short*)(smraw + OB_G);
  unsigned* sM2 = (unsigned*)(smraw + OB_M2);
  float* sW3f = (float*)(smraw + OB_W3F);
  float* sR   = (float*)(smraw + OB_R);
  float* sPRM = (float*)(smraw + OB_PRM);   // 2 x 768 floats
  float* sGZ  = (float*)(smraw + OB_GZ);
  float* sZ1  = (float*)(smraw + OB_Z1);
  float* sLD  = (float*)(smraw + OB_LD);
  float* sZQ  = (float*)(smraw + OB_ZQ);
  float* sRed = (float*)(smraw + OB_RED);

  const int tid  = threadIdx.x;
  const int lane = tid & 63;
  const int w    = __builtin_amdgcn_readfirstlane(tid >> 6);  // 0..11
  const int lm   = lane & 15, lq = lane >> 4;    // MFMA lane coords
  const int blk  = blockIdx.x;

  // ---- init ----
  float z_a = 0.f, z_b = 0.f;     // z[i], z[6+i] held by tid<384 (i=tid>>6)
  if (tid < 384) {
    int i = tid >> 6, e = tid & 63;
    z_a = yz[(blk * EPB + e) * 12 + i];
    z_b = yz[(blk * EPB + e) * 12 + 6 + i];
    sZ1[i * EPB + e] = z_b;
  }
  if (tid < 64) { sLD[tid] = 0.f; sZQ[tid] = 0.f; }
  if (tid == 0) sRed[0] = 0.f;
  for (int idx = tid; idx < 2304; idx += 768) sGZ[idx] = 0.f;
  sPRM[tid] = 0.f; sPRM[768 + tid] = 0.f;
  for (int idx = tid; idx < 72 * EPB; idx += 768) {
    int rt = idx >> 6, ee = idx & 63;
    sR[idx] = jp[(blk * EPB + ee) * 72 + rt];
  }
  __syncthreads();

  for (int l = NLAYER - 1; l >= 0; --l) {
    const float* W1l = W1 + l * HID * 6;
    const float* b1l = b1 + l * HID;
    const float* b2l = b2 + l * HID;
    const float* W3l = W3 + l * NDIN * HID;
    const float* b3l = b3 + l * NDIN;
    const unsigned short* w2bl = w2b + l * HID * HID;
    const unsigned short* w2tl = w2t + l * HID * HID;
    float* cur = sPRM + (l & 1) * 768;
    float* prv = sPRM + ((l + 1) & 1) * 768;

    // ==== Phase A: stage W1+W3f, zero cur+mask, V5(l+1), F1(l) ==========
    if (tid < 192) {
      const float* wr = W1l + tid * 6;
      uint4 pk;
      pk.x = pk2(wr[0], wr[1]); pk.y = pk2(wr[2], wr[3]);
      pk.z = pk2(wr[4], wr[5]); pk.w = 0;
      *(uint4*)(smraw + OB_W1 + tid * 16) = pk;
    }
    for (int idx = tid; idx < 2304; idx += 768) {
      int t = idx / 192, j = idx - t * 192;
      sW3f[j * W3ST + t] = W3l[idx];
    }
    cur[tid] = 0.f;
    if (tid < 512) sM2[tid] = 0u;
    if (l != NLAYER - 1) {                          // V5 of layer l+1
      for (int idx = tid; idx < 2304; idx += 768) {
        int i = idx / 384, rem = idx - i * 384;     // rem = r*64 + eg
        int r = rem >> 6, eg = rem & 63;
        float r1  = sR[(r * 12 + i) * EPB + eg];
        float r2o = sR[(r * 12 + 6 + i) * EPB + eg];
        float es  = prv[(2 * i + 1) * EPB + eg];
        sR[(r * 12 + i) * EPB + eg]     = r2o + sGZ[i * 384 + rem];
        sR[(r * 12 + 6 + i) * EPB + eg] = r1 * es;
        sGZ[i * 384 + rem] = 0.f;
      }
    }
    {                                               // F1: 16 rows per wave-grp
      int e = tid & 63, g12 = tid >> 6;
      float z1v[6];
      #pragma unroll
      for (int i = 0; i < 6; ++i) z1v[i] = sZ1[i * EPB + e];
      int jb = g12 * 16;
      #pragma unroll
      for (int jj = 0; jj < 16; ++jj) {
        int j = jb + jj;                            // wave-uniform row
        float acc = b1l[j];
        #pragma unroll
        for (int i = 0; i < 6; ++i) acc = fmaf(W1l[j * 6 + i], z1v[i], acc);
        sH1b[e * EST + j] = f2bf(fmaxf(acc, 0.f));
      }
    }
    __syncthreads();

    // ==== Phase B: F2 MFMA (1 m-tile x 4 n-tiles/wave) + prm + mask =====
    {
      f4v acc4[4] = {{0,0,0,0},{0,0,0,0},{0,0,0,0},{0,0,0,0}};
      #pragma unroll 2
      for (int kk = 0; kk < 6; ++kk) {
        int jo = kk * 32 + lq * 8;
        s8v A = *(const s8v*)(w2bl + (w * 16 + lm) * HID + jo);
        #pragma unroll
        for (int nt = 0; nt < 4; ++nt) {
          s8v B = *(const s8v*)&sH1b[(nt * 16 + lm) * EST + jo];
          acc4[nt] = MFMA16(A, B, acc4[nt]);
        }
      }
      int jb2 = w * 16 + lq * 4;
      float bb[4];
      #pragma unroll
      for (int rg = 0; rg < 4; ++rg) bb[rg] = b2l[jb2 + rg];
      #pragma unroll
      for (int nt = 0; nt < 4; ++nt) {
        int e2 = nt * 16 + lm;
        float hv[4];
        unsigned nib = 0;
        #pragma unroll
        for (int rg = 0; rg < 4; ++rg) {
          hv[rg] = fmaxf(acc4[nt][rg] + bb[rg], 0.f);
          nib |= (hv[rg] > 0.f ? 1u : 0u) << rg;
        }
        atomicOr(&sM2[e2 * 8 + (jb2 >> 5)], nib << (jb2 & 31));
        float pp[12];
        #pragma unroll
        for (int t = 0; t < 12; ++t) pp[t] = 0.f;
        #pragma unroll
        for (int rg = 0; rg < 4; ++rg) {
          const float* w3r = sW3f + (jb2 + rg) * W3ST;
          float v = hv[rg];
          #pragma unroll
          for (int t = 0; t < 12; ++t) pp[t] = fmaf(w3r[t], v, pp[t]);
        }
        #pragma unroll
        for (int t = 0; t < 12; ++t) {
          float v = pp[t];
          v += __shfl_xor(v, 16);
          v += __shfl_xor(v, 32);
          if (lane < 16) atomicAdd(&cur[t * EPB + nt * 16 + lane], v);
        }
      }
    }
    __syncthreads();

    // ==== Phase C: U — coupling update; cur becomes tf@2i, es@2i+1 ======
    if (tid < 384) {
      int i = tid >> 6, e = tid & 63;
      float sh = b3l[2 * i]     + cur[(2 * i) * EPB + e];
      float sr = b3l[2 * i + 1] + cur[(2 * i + 1) * EPB + e];
      float s  = 2.f * tanhf(0.5f * sr);
      float es = expf(s), en = expf(-s);
      float tv = z_a - sh;
      z_a = z_b;
      z_b = tv * en;
      sZ1[i * EPB + e] = z_b;
      cur[(2 * i) * EPB + e]     = tv * (1.f - 0.25f * s * s);  // tf
      cur[(2 * i + 1) * EPB + e] = es;                          // es
      atomicAdd(&sLD[e], -s);
    }
    __syncthreads();

    // ==== Phases D/E per 32-element half (G buffer shared) ==============
    #pragma unroll 1
    for (int h = 0; h < 2; ++h) {
      // -- D: V2 (6 rows, one 8-wide j-slab per thread) --
      {
        int e_l = tid & 31, sl8 = tid >> 5, slab = sl8 * 8;
        int e_g = h * 32 + e_l;
        float tf6[6];
        #pragma unroll
        for (int i = 0; i < 6; ++i) tf6[i] = cur[(2 * i) * EPB + e_g];
        unsigned m8 = (sM2[e_g * 8 + (sl8 >> 2)] >> ((sl8 & 3) * 8)) & 0xffu;
        float weff[8][6];
        #pragma unroll
        for (int jj = 0; jj < 8; ++jj) {
          const float* wrow = sW3f + (slab + jj) * W3ST;
          #pragma unroll
          for (int c = 0; c < 6; ++c)
            weff[jj][c] = fmaf(tf6[c], wrow[2 * c + 1], wrow[2 * c]);
        }
        #pragma unroll
        for (int r = 0; r < 6; ++r) {
          float g[8];
          #pragma unroll
          for (int jj = 0; jj < 8; ++jj) g[jj] = 0.f;
          #pragma unroll
          for (int c = 0; c < 6; ++c) {
            float r1 = sR[(r * 12 + c) * EPB + e_g];
            #pragma unroll
            for (int jj = 0; jj < 8; ++jj)
              g[jj] = fmaf(weff[jj][c], r1, g[jj]);
          }
          unsigned* dst = (unsigned*)sGb + (((r * 32 + e_l) * EST + slab) >> 1);
          #pragma unroll
          for (int pr = 0; pr < 4; ++pr) {
            float v0 = ((m8 >> (2 * pr)) & 1u)     ? g[2 * pr] : 0.f;
            float v1 = ((m8 >> (2 * pr + 1)) & 1u) ? g[2 * pr + 1] : 0.f;
            dst[pr] = pk2(v0, v1);
          }
        }
      }
      __syncthreads();

      // -- E: V3 MFMA (3x4 tiles/wave) + mask1 + W1^T epilogue -> sGZ --
      {
        const int mtg3 = (w & 3) * 3;
        const int ntg4 = (w >> 2) * 4;
        f4v acc[3][4] = {{{0,0,0,0},{0,0,0,0},{0,0,0,0},{0,0,0,0}},
                         {{0,0,0,0},{0,0,0,0},{0,0,0,0},{0,0,0,0}},
                         {{0,0,0,0},{0,0,0,0},{0,0,0,0},{0,0,0,0}}};
        #pragma unroll 2
        for (int kk = 0; kk < 6; ++kk) {
          int jo = kk * 32 + lq * 8;
          s8v A[3], B[4];
          #pragma unroll
          for (int p = 0; p < 3; ++p)
            A[p] = *(const s8v*)(w2tl + ((mtg3 + p) * 16 + lm) * HID + jo);
          #pragma unroll
          for (int q = 0; q < 4; ++q)
            B[q] = *(const s8v*)&sGb[((ntg4 + q) * 16 + lm) * EST + jo];
          #pragma unroll
          for (int p = 0; p < 3; ++p)
            #pragma unroll
            for (int q = 0; q < 4; ++q)
              acc[p][q] = MFMA16(A[p], B[q], acc[p][q]);
        }
        float pz[4][6];
        #pragma unroll
        for (int q = 0; q < 4; ++q)
          #pragma unroll
          for (int i = 0; i < 6; ++i) pz[q][i] = 0.f;
        #pragma unroll
        for (int p = 0; p < 3; ++p) {
          int kb = (mtg3 + p) * 16 + lq * 4;
          float w1v[4][6];
          #pragma unroll
          for (int rg = 0; rg < 4; ++rg) {
            uint4 wr = *(const uint4*)(smraw + OB_W1 + (kb + rg) * 16);
            w1v[rg][0] = blo(wr.x); w1v[rg][1] = bhi(wr.x);
            w1v[rg][2] = blo(wr.y); w1v[rg][3] = bhi(wr.y);
            w1v[rg][4] = blo(wr.z); w1v[rg][5] = bhi(wr.z);
          }
          #pragma unroll
          for (int q = 0; q < 4; ++q) {
            int e_l = (((ntg4 + q) & 1) << 4) + lm;   // col & 31
            const unsigned* mp =
              (const unsigned*)&sH1b[(h * 32 + e_l) * EST + kb];
            unsigned mm0 = mp[0], mm1 = mp[1];
            unsigned short hb[4] = {
              (unsigned short)(mm0 & 0xffff), (unsigned short)(mm0 >> 16),
              (unsigned short)(mm1 & 0xffff), (unsigned short)(mm1 >> 16)};
            #pragma unroll
            for (int rg = 0; rg < 4; ++rg) {
              float val = hb[rg] ? acc[p][q][rg] : 0.f;
              #pragma unroll
              for (int i = 0; i < 6; ++i)
                pz[q][i] = fmaf(w1v[rg][i], val, pz[q][i]);
            }
          }
        }
        #pragma unroll
        for (int q = 0; q < 4; ++q)
          #pragma unroll
          for (int i = 0; i < 6; ++i) {
            float v = pz[q][i];
            v += __shfl_xor(v, 16);
            v += __shfl_xor(v, 32);
            if (lane < 16) {
              int col = (ntg4 + q) * 16 + lane;
              atomicAdd(&sGZ[i * 384 + (col >> 5) * 64 + h * 32 + (col & 31)], v);
            }
          }
      }
      __syncthreads();
    }
  }

  // ---- final V5 (layer 0, parity 0) + z/lp; then jp writeback ----
  {
    float* prv0 = sPRM;
    for (int idx = tid; idx < 2304; idx += 768) {
      int i = idx / 384, rem = idx - i * 384;
      int r = rem >> 6, eg = rem & 63;
      float r1  = sR[(r * 12 + i) * EPB + eg];
      float r2o = sR[(r * 12 + 6 + i) * EPB + eg];
      float es  = prv0[(2 * i + 1) * EPB + eg];
      sR[(r * 12 + i) * EPB + eg]     = r2o + sGZ[i * 384 + rem];
      sR[(r * 12 + 6 + i) * EPB + eg] = r1 * es;
    }
  }
  if (tid < 384) {
    int i = tid >> 6, e = tid & 63;
    yz[(blk * EPB + e) * 12 + i]     = z_a;
    yz[(blk * EPB + e) * 12 + 6 + i] = z_b;
    atomicAdd(&sZQ[e], fmaf(z_a, z_a, z_b * z_b));
  }
  __syncthreads();
  if (tid < 64)
    out_lp[blk * EPB + tid] = sLD[tid] - 11.027262398456072f - 0.5f * sZQ[tid];

  float part = 0.f;
  for (int idx = tid; idx < 72 * EPB; idx += 768) {
    int rt = idx >> 6, ee = idx & 63;
    float v = sR[idx];
    jp[(blk * EPB + ee) * 72 + rt] = v;
    part = fmaf(v, v, part);
  }
  #pragma unroll
  for (int off = 32; off > 0; off >>= 1) part += __shfl_down(part, off, 64);
  if ((tid & 63) == 0) atomicAdd(&sRed[0], part);
  __syncthreads();
  if (tid == 0) atomicAdd(ws_sum, sRed[0]);
}

// ---------------------------------------------------------------------
// kl_kernel: one thread per element (unchanged from R3..R12 PASS).
__global__ __launch_bounds__(256) void kl_kernel(
    const float* __restrict__ zin, const float* __restrict__ jpin,
    const float* __restrict__ Wsym, const float* __restrict__ lvd,
    const float* __restrict__ ws_sum, float* __restrict__ out_kl) {
  int elem = blockIdx.x * 256 + threadIdx.x;
  float z[12];
  #pragma unroll
  for (int i = 0; i < 12; ++i) z[i] = zin[elem * 12 + i];
  float scale = 1.0f / sqrtf(ws_sum[0]);
  float Jp[6][12];
  #pragma unroll
  for (int n = 0; n < 6; ++n)
    #pragma unroll
    for (int j = 0; j < 12; ++j)
      Jp[n][j] = jpin[elem * 72 + n * 12 + j] * scale;

  float Sq[78];
  #pragma unroll
  for (int i = 0; i < 78; ++i) Sq[i] = 0.f;
  float tq = 0.f, tpq = 0.f;

  for (int m = 0; m < NBASE; ++m) {
    const float* Wm = Wsym + m * 144;
    float jq[12];
    #pragma unroll
    for (int j = 0; j < 12; ++j) {
      float acc = 0.f;
      #pragma unroll
      for (int i = 0; i < 12; ++i)
        acc = fmaf(Wm[j * 12 + i] - Wm[i * 12 + j], z[i], acc);
      jq[j] = acc;
    }
    #pragma unroll
    for (int i = 0; i < 12; ++i) {
      tq = fmaf(jq[i], jq[i], tq);
      #pragma unroll
      for (int j = 0; j <= i; ++j)
        Sq[i * (i + 1) / 2 + j] = fmaf(jq[i], jq[j], Sq[i * (i + 1) / 2 + j]);
    }
    #pragma unroll
    for (int n = 0; n < 6; ++n) {
      float d = 0.f;
      #pragma unroll
      for (int j = 0; j < 12; ++j) d = fmaf(Jp[n][j], jq[j], d);
      tpq = fmaf(d, d, tpq);
    }
  }

  float Dv[12], Db[12];
  #pragma unroll
  for (int j = 0; j < 12; ++j) Dv[j] = expf(-lvd[j]);

  float mh = 0.f;
  #pragma unroll
  for (int i = 0; i < 12; ++i) mh += Sq[i * (i + 1) / 2 + i] + Dv[i];
  float norm_H = fmaxf(mh * (1.f / 12.f), 1e-6f);
  #pragma unroll
  for (int i = 0; i < 12; ++i) Sq[i * (i + 1) / 2 + i] += Dv[i] + 1e-3f * norm_H;
  float sumDb = 0.f;
  #pragma unroll
  for (int j = 0; j < 12; ++j) { Db[j] = Dv[j] + 1e-3f * norm_H; sumDb += Db[j]; }

  float M[21];
  #pragma unroll
  for (int n = 0; n < 6; ++n)
    #pragma unroll
    for (int mm = 0; mm <= n; ++mm) {
      float acc = 0.f;
      #pragma unroll
      for (int j = 0; j < 12; ++j) acc = fmaf(Jp[n][j], Jp[mm][j], acc);
      M[n * (n + 1) / 2 + mm] = acc;
    }
  float md = 0.f;
  #pragma unroll
  for (int i = 0; i < 6; ++i) md += M[i * (i + 1) / 2 + i];
  float norm_M = fmaxf(md * (1.f / 6.f) + EPSP, 1e-6f);
  #pragma unroll
  for (int i = 0; i < 6; ++i) M[i * (i + 1) / 2 + i] += EPSP + 1e-3f * norm_M;

  float trace_p = 0.f;
  #pragma unroll
  for (int n = 0; n < 6; ++n)
    #pragma unroll
    for (int j = 0; j < 12; ++j)
      trace_p = fmaf(Jp[n][j] * Jp[n][j], Db[j], trace_p);

  float trace = (EPSP + 1e-3f * norm_M) * (sumDb + tq) + trace_p + tpq;

  float ldM = 0.f;
  #pragma unroll
  for (int jc = 0; jc < 6; ++jc) {
    float d = M[jc * (jc + 1) / 2 + jc];
    #pragma unroll
    for (int k = 0; k < jc; ++k) d -= M[jc * (jc + 1) / 2 + k] * M[jc * (jc + 1) / 2 + k];
    d = sqrtf(d);
    ldM += logf(d);
    float di = 1.f / d;
    M[jc * (jc + 1) / 2 + jc] = d;
    #pragma unroll
    for (int i2 = jc + 1; i2 < 6; ++i2) {
      float v = M[i2 * (i2 + 1) / 2 + jc];
      #pragma unroll
      for (int k = 0; k < jc; ++k) v -= M[i2 * (i2 + 1) / 2 + k] * M[jc * (jc + 1) / 2 + k];
      M[i2 * (i2 + 1) / 2 + jc] = v * di;
    }
  }

  float ldH = 0.f;
  #pragma unroll
  for (int jc = 0; jc < 12; ++jc) {
    float d = Sq[jc * (jc + 1) / 2 + jc];
    #pragma unroll
    for (int k = 0; k < jc; ++k) d -= Sq[jc * (jc + 1) / 2 + k] * Sq[jc * (jc + 1) / 2 + k];
    d = sqrtf(d);
    ldH += logf(d);
    float di = 1.f / d;
    Sq[jc * (jc + 1) / 2 + jc] = d;
    #pragma unroll
    for (int i2 = jc + 1; i2 < 12; ++i2) {
      float v = Sq[i2 * (i2 + 1) / 2 + jc];
      #pragma unroll
      for (int k = 0; k < jc; ++k) v -= Sq[i2 * (i2 + 1) / 2 + k] * Sq[jc * (jc + 1) / 2 + k];
      Sq[i2 * (i2 + 1) / 2 + jc] = v * di;
    }
  }

  float logdet_p = 2.f * ldM + 6.f * logf(EPSP);
  float logdet_q = 2.f * ldH;
  out_kl[elem] = 0.5f * (trace - (logdet_p + logdet_q) - 12.f);
}

// ---------------------------------------------------------------------
extern "C" void kernel_launch(void* const* d_in, const int* in_sizes, int n_in,
                              void* d_out, int out_size, void* d_ws, size_t ws_size,
                              hipStream_t stream) {
  (void)in_sizes; (void)n_in; (void)out_size; (void)ws_size;
  float* y    = (float*)d_in[0];   // consumed, then overwritten with z
  float* Jp   = (float*)d_in[1];   // consumed, then overwritten with pullback Jp
  const float* W1   = (const float*)d_in[2];
  const float* b1   = (const float*)d_in[3];
  const float* W2   = (const float*)d_in[4];
  const float* b2   = (const float*)d_in[5];
  const float* W3   = (const float*)d_in[6];
  const float* b3   = (const float*)d_in[7];
  const float* Wsym = (const float*)d_in[8];
  const float* lvd  = (const float*)d_in[9];
  float* out = (float*)d_out;      // fp32: [log_prob (B), kl (B)]

  float* ws_sum = (float*)d_ws;
  unsigned short* w2b = (unsigned short*)((char*)d_ws + 256);
  unsigned short* w2t = (unsigned short*)((char*)d_ws + 256 +
                                          NLAYER * HID * HID * 2);
  hipMemsetAsync(d_ws, 0, 4, stream);

  hipFuncSetAttribute((const void*)flow_kernel,
                      hipFuncAttributeMaxDynamicSharedMemorySize, SMEM_BYTES);

  prep_kernel<<<3456, 256, 0, stream>>>(W2, w2b, w2t);
  flow_kernel<<<BTOT / EPB, 768, SMEM_BYTES, stream>>>(
      y, Jp, W1, b1, b2, W3, b3, w2b, w2t, ws_sum, out);
  kl_kernel<<<64, 256, 0, stream>>>(y, Jp, Wsym, lvd, ws_sum, out + BTOT);
}